// Round 6
// baseline (190.271 us; speedup 1.0000x reference)
//
#include <hip/hip_runtime.h>

#define BB   8192   // batch (M)
#define DIN  4096   // K
#define DOUT 2048   // N

typedef unsigned short ushort_t;
typedef __attribute__((ext_vector_type(8))) short bf16x8;   // 8 bf16 (4 VGPRs)
typedef __attribute__((ext_vector_type(4))) float f32x4;    // 4 fp32 acc

// round-to-nearest-even fp32 -> bf16 bits (used by maskT)
__device__ inline ushort_t f2bf(float f) {
    union { float f; unsigned u; } v; v.f = f;
    unsigned u = v.u;
    return (ushort_t)((u + 0x7fffu + ((u >> 16) & 1u)) >> 16);
}

// async global->LDS, 16B per lane; LDS dest = wave-uniform base (+lane*16 implicit)
#define GLOAD16(g, s)                                                        \
    __builtin_amdgcn_global_load_lds(                                        \
        (const __attribute__((address_space(1))) void*)(g),                  \
        (__attribute__((address_space(3))) void*)(s), 16, 0, 0)

#define FENCE() asm volatile("" ::: "memory")
#define BAR()   do { FENCE(); __builtin_amdgcn_s_barrier(); FENCE(); } while (0)
#define VMCNT(n) asm volatile("s_waitcnt vmcnt(" #n ")" ::: "memory")
#define LGKM0()  asm volatile("s_waitcnt lgkmcnt(0)" ::: "memory")

// ---------------- pre-pass: WT[n][k] = bf16(kernel[k][n]*map[k][n]) ----------------
__global__ __launch_bounds__(256) void maskT(const float* __restrict__ Kn,
                                             const float* __restrict__ Mp,
                                             ushort_t* __restrict__ WT) {
    __shared__ ushort_t t[32][33];
    const int n0 = blockIdx.x * 32;
    const int k0 = blockIdx.y * 32;
    const int tx = threadIdx.x, ty = threadIdx.y;
    #pragma unroll
    for (int i = ty; i < 32; i += 8) {
        size_t idx = (size_t)(k0 + i) * DOUT + (n0 + tx);
        t[i][tx] = f2bf(Kn[idx] * Mp[idx]);
    }
    __syncthreads();
    #pragma unroll
    for (int i = ty; i < 32; i += 8) {
        WT[(size_t)(n0 + i) * DIN + (k0 + tx)] = t[tx][i];
    }
}

// ---------------- main GEMM: 256x256 tile, BK=64, 8 waves ----------------
// A is fp32 in HBM: reg-staged (global->reg->cvt->ds_write, T14 split), so no
// separate conversion pass. B (bf16 WT) staged via gload_lds with
// inverse-swizzled global source. Swizzle convention both sides:
// byte_col ^= (row&7)<<4 within each 128B row.
// LDS (dynamic 128 KiB): buf d: A half h at d*65536 + h*16384 ([128][64] bf16),
//                        B half h at d*65536 + 32768 + h*16384.
// Phases per K-tile: q=(mh,ks): q0=(0,0) q1=(1,0) q2=(0,1) q3=(1,1); 16 MFMA each.
// Issue: q0: A-h0(4 dwordx4) + B(4 gload_lds). q2 post-MFMA: VMCNT(4), write A-h0,
// issue A-h1. q3 post-MFMA: VMCNT(0), write A-h1, lgkmcnt(0). Leash >=1.2 phases.
__global__ __launch_bounds__(512) void gemm8(const float* __restrict__ A,      // [M][K] f32
                                             const ushort_t* __restrict__ BT,  // [N][K] bf16
                                             const float* __restrict__ bias,   // [N]
                                             float* __restrict__ C) {          // [M][N] f32
    constexpr int K = DIN, N = DOUT;
    constexpr int NT = K / 64;           // 64 K-tiles
    extern __shared__ char sb[];         // 128 KiB

    const int tid  = threadIdx.x;
    const int lane = tid & 63;
    const int w    = tid >> 6;           // wave 0..7
    const int wr   = w >> 2;             // 0..1  (M half)
    const int wcn  = w & 3;              // 0..3  (N quarter)
    const int l15  = lane & 15;

    // bijective XCD swizzle: 256 blocks, 256 % 8 == 0
    const int orig = blockIdx.y * 8 + blockIdx.x;
    const int swz  = (orig & 7) * 32 + (orig >> 3);
    const int n0   = (swz & 7) * 256;    // N tile
    const int m0   = (swz >> 3) * 256;   // M tile

    // ---- B staging: chunk (h,c) = rows c*8..c*8+7 of half h; lane l -> row c*8+(l>>3),
    // LDS slot (l&7); global col16 = (l&7)^(l>>3)  (inverse swizzle, row&7 = l>>3)
    const int srow = lane >> 3;
    const int scol = ((lane & 7) ^ srow) * 8;
    const ushort_t* Bb = BT + (size_t)(n0 + srow) * K + scol;
    auto stgB = [&](int buf, int kt, int h, int c) {
        GLOAD16(Bb + (size_t)(h * 128 + c * 8) * K + kt * 64,
                sb + buf * 65536 + 32768 + h * 16384 + c * 1024);
    };

    // ---- A reg staging: half hf = rows hf*128..+127; load j -> row hf*128+j*32+(tid>>4),
    // floats (tid&15)*4..+3. Per-instruction: 16 lanes = 256B contiguous (coalesced).
    const float* Aft = A + (size_t)(m0 + (tid >> 4)) * K + (tid & 15) * 4;
    float4 apf[4];
    auto issueA = [&](int kt, int hf) {
        #pragma unroll
        for (int j = 0; j < 4; ++j)
            apf[j] = *(const float4*)(Aft + (size_t)(hf * 128 + j * 32) * K + kt * 64);
    };
    // LDS write offset: row*128 + ((col8*8) ^ ((row&7)<<4)); row&7 = (tid>>4)&7
    const int awoff = (tid >> 4) * 128 + (((tid & 15) * 8) ^ (((tid >> 4) & 7) << 4));
    auto writeA = [&](int buf, int hf) {
        #pragma unroll
        for (int j = 0; j < 4; ++j) {
            uint2 p;
            asm("v_cvt_pk_bf16_f32 %0, %1, %2" : "=v"(p.x) : "v"(apf[j].x), "v"(apf[j].y));
            asm("v_cvt_pk_bf16_f32 %0, %1, %2" : "=v"(p.y) : "v"(apf[j].z), "v"(apf[j].w));
            *(uint2*)(sb + buf * 65536 + hf * 16384 + j * 4096 + awoff) = p;
        }
    };

    // ---- fragment ds_read: row = <mult of 16> + l15 -> row&7 = l15&7 ----
    const int fxor = (l15 & 7) << 4;
    const int kq   = (lane >> 4) * 16;   // 16B col within K=32 sub-tile

    f32x4 acc[8][4] = {};   // 8 m-frags x 4 n-frags
    bf16x8 bfk[4];          // B frags for current ks (persist 2 phases)

    // ---- prologue: serialized (keeps apf at 4 regs), tile 0 -> buf 0
    issueA(0, 0); VMCNT(0); writeA(0, 0);
    issueA(0, 1); VMCNT(0); writeA(0, 1);
    stgB(0, 0, 0, w); stgB(0, 0, 0, 8 + w);
    stgB(0, 0, 1, w); stgB(0, 0, 1, 8 + w);
    VMCNT(0); LGKM0();
    BAR();

    for (int t = 0; t < NT; ++t) {
        const int  cur = t & 1;
        const int  nxt = cur ^ 1;
        const bool pf  = (t + 1 < NT);
        const char* Abase = sb + cur * 65536 + wr * 16384;
        const char* Bbase = sb + cur * 65536 + 32768 + wcn * 8192;

        #pragma unroll
        for (int q = 0; q < 4; ++q) {
            const int mh = q & 1;        // m-half of the wave's 8 m-frags
            const int ks = q >> 1;       // K=32 sub-tile within BK=64
            bf16x8 af[4];
            #pragma unroll
            for (int mm = 0; mm < 4; ++mm)
                af[mm] = *(const bf16x8*)(Abase + (mh * 4 + mm) * 2048 + l15 * 128 +
                                          ((ks * 64 + kq) ^ fxor));
            if (mh == 0) {
                #pragma unroll
                for (int n = 0; n < 4; ++n)
                    bfk[n] = *(const bf16x8*)(Bbase + n * 2048 + l15 * 128 +
                                              ((ks * 64 + kq) ^ fxor));
            }
            if (q == 0 && pf) {
                issueA(t + 1, 0);                              // 4 dwordx4 (oldest)
                stgB(nxt, t + 1, 0, w); stgB(nxt, t + 1, 0, 8 + w);
                stgB(nxt, t + 1, 1, w); stgB(nxt, t + 1, 1, 8 + w);
            }
            BAR();
            __builtin_amdgcn_s_setprio(1);
            #pragma unroll
            for (int mm = 0; mm < 4; ++mm)
                #pragma unroll
                for (int n = 0; n < 4; ++n)
                    acc[mh * 4 + mm][n] = __builtin_amdgcn_mfma_f32_16x16x32_bf16(
                        af[mm], bfk[n], acc[mh * 4 + mm][n], 0, 0, 0);
            __builtin_amdgcn_s_setprio(0);
            if (q == 2 && pf) {
                VMCNT(4);            // A-h0 (oldest 4 of 8) landed; B may be in flight
                writeA(nxt, 0);      // frees apf
                issueA(t + 1, 1);    // refill apf with A-h1
            }
            if (q == 3 && pf) {
                VMCNT(0);            // B (leash 3.7 ph) + A-h1 (leash 1.2 ph) landed
                writeA(nxt, 1);
                LGKM0();             // ds_writes visible before buffer-swap barrier
            }
            BAR();
        }
    }

    // ---- epilogue: C/D layout col=lane&15, row=(lane>>4)*4+j; fused bias ----
    #pragma unroll
    for (int n = 0; n < 4; ++n) {
        const int col = n0 + wcn * 64 + n * 16 + l15;
        const float bv = bias[col];
        #pragma unroll
        for (int m = 0; m < 8; ++m) {
            const int r0 = m0 + wr * 128 + m * 16 + (lane >> 4) * 4;
            #pragma unroll
            for (int j = 0; j < 4; ++j)
                C[(size_t)(r0 + j) * N + col] = acc[m][n][j] + bv;
        }
    }
}

// ---------------- fallback (ws too small): fp32 LDS-tiled GEMM ----------------
__global__ __launch_bounds__(1024) void gemm_fb(const float* __restrict__ A,
                                                const float* __restrict__ Kn,
                                                const float* __restrict__ Mp,
                                                const float* __restrict__ bias,
                                                float* __restrict__ C) {
    __shared__ float As[32][33];
    __shared__ float Bs[32][33];
    const int tx = threadIdx.x, ty = threadIdx.y;
    const int row = blockIdx.y * 32 + ty;
    const int col = blockIdx.x * 32 + tx;
    float acc = 0.f;
    for (int kt = 0; kt < DIN; kt += 32) {
        As[ty][tx] = A[(size_t)row * DIN + kt + tx];
        size_t bidx = (size_t)(kt + ty) * DOUT + col;
        Bs[ty][tx] = Kn[bidx] * Mp[bidx];
        __syncthreads();
        #pragma unroll
        for (int kk = 0; kk < 32; ++kk)
            acc += As[ty][kk] * Bs[kk][tx];
        __syncthreads();
    }
    C[(size_t)row * DOUT + col] = acc + bias[col];
}

extern "C" void kernel_launch(void* const* d_in, const int* in_sizes, int n_in,
                              void* d_out, int out_size, void* d_ws, size_t ws_size,
                              hipStream_t stream) {
    const float* inputs = (const float*)d_in[0];   // [8192,4096]
    const float* kernel = (const float*)d_in[1];   // [4096,2048]
    const float* bias   = (const float*)d_in[2];   // [2048]
    const float* map    = (const float*)d_in[3];   // [4096,2048]
    float* out = (float*)d_out;                    // [8192,2048]

    const size_t wbytes = (size_t)DIN * DOUT * sizeof(ushort_t); // 16 MiB

    if (ws_size >= wbytes) {
        ushort_t* WT = (ushort_t*)d_ws;

        static bool attr_set = false;
        if (!attr_set) {
            hipFuncSetAttribute((const void*)gemm8,
                                hipFuncAttributeMaxDynamicSharedMemorySize, 131072);
            attr_set = true;
        }

        maskT<<<dim3(DOUT / 32, DIN / 32), dim3(32, 8), 0, stream>>>(kernel, map, WT);
        gemm8<<<dim3(DOUT / 256, BB / 256), 512, 131072, stream>>>(inputs, WT, bias, out);
    } else {
        gemm_fb<<<dim3(DOUT / 32, BB / 32), dim3(32, 32), 0, stream>>>(inputs, kernel, map,
                                                                       bias, out);
    }
}